// Round 6
// baseline (766.368 us; speedup 1.0000x reference)
//
#include <hip/hip_runtime.h>
#include <hip/hip_bf16.h>
#include <stdint.h>

#define B_    2
#define S_    4096
#define H_    16
#define NOPE  128
#define ROPE  64
#define QKD   192
#define VD    128
#define R_    512
#define STRW  16
#define NBLK  255
#define TOPKN 16
#define SCALEF 0.07216878364870323f
#define BIGF   1000000000.0f

typedef __attribute__((ext_vector_type(8))) _Float16 h8_t;   // 8 fp16 (4 VGPRs)
typedef __attribute__((ext_vector_type(4))) float f4_t;      // MFMA acc

#define MFH(a,b,c) __builtin_amdgcn_mfma_f32_16x16x32_f16((a),(b),(c),0,0,0)

__device__ inline unsigned short f2h(float x) {
    _Float16 hh = (_Float16)x;
    return *(unsigned short*)&hh;
}
// 2-way fp16 split: x ~= h + l, residual ~2^-22 rel
__device__ inline void split2h(float x, unsigned short& h, unsigned short& l) {
    _Float16 hh = (_Float16)x;
    _Float16 ll = (_Float16)(x - (float)hh);
    h = *(unsigned short*)&hh;
    l = *(unsigned short*)&ll;
}

// ---------------------------------------------------------------------------
// G1: cmp_kv = window(kv_lora) @ W_cmp_kv   (M=510, N=512, K=16384)
// Tile 128x64, split-K=16, atomicAdd epilogue (out pre-zeroed).
// PROVEN fp32 path (topk ranking is knife-edge sensitive to cmp_kv rounding;
// fp16-split MFMA failed: W ~ 0.008 -> low-plane subnormal -> flushed in MFMA).
// ---------------------------------------------------------------------------
__global__ __launch_bounds__(256) void g1_cmpkv(const float* __restrict__ A,
                                                const float* __restrict__ W,
                                                float* __restrict__ out) {
    __shared__ float As[16][132];
    __shared__ float Bs[16][68];
    const int t  = threadIdx.x;
    const int m0 = blockIdx.x * 128;
    const int n0 = blockIdx.y * 64;
    const int k0 = blockIdx.z * 1024;
    const int tr = t >> 4, tc = t & 15;
    float acc[8][4];
#pragma unroll
    for (int i = 0; i < 8; ++i)
#pragma unroll
        for (int j = 0; j < 4; ++j) acc[i][j] = 0.f;

    for (int kt = 0; kt < 1024; kt += 16) {
        __syncthreads();
#pragma unroll
        for (int i = 0; i < 2; ++i) {
            int f = t + i * 256;
            int r = f >> 2, kq = (f & 3) * 4;
            int m = m0 + r;
            float4 av = make_float4(0.f, 0.f, 0.f, 0.f);
            if (m < 510) {
                int b = (m >= NBLK) ? 1 : 0;
                int n = m - b * NBLK;
                av = *(const float4*)(A + (size_t)(b * S_ + n * STRW) * R_ + k0 + kt + kq);
            }
            As[kq + 0][r] = av.x; As[kq + 1][r] = av.y;
            As[kq + 2][r] = av.z; As[kq + 3][r] = av.w;
        }
        {
            int kb = t >> 4, nq = (t & 15) * 4;
            *(float4*)&Bs[kb][nq] =
                *(const float4*)(W + (size_t)(k0 + kt + kb) * R_ + n0 + nq);
        }
        __syncthreads();
#pragma unroll
        for (int kk = 0; kk < 16; ++kk) {
            float a0[8], b0[4];
            float4 x = *(const float4*)&As[kk][8 * tr];
            float4 y = *(const float4*)&As[kk][8 * tr + 4];
            a0[0] = x.x; a0[1] = x.y; a0[2] = x.z; a0[3] = x.w;
            a0[4] = y.x; a0[5] = y.y; a0[6] = y.z; a0[7] = y.w;
            float4 z = *(const float4*)&Bs[kk][4 * tc];
            b0[0] = z.x; b0[1] = z.y; b0[2] = z.z; b0[3] = z.w;
#pragma unroll
            for (int i = 0; i < 8; ++i)
#pragma unroll
                for (int j = 0; j < 4; ++j)
                    acc[i][j] = fmaf(a0[i], b0[j], acc[i][j]);
        }
    }
#pragma unroll
    for (int i = 0; i < 8; ++i) {
        int m = m0 + 8 * tr + i;
        if (m < 510) {
#pragma unroll
            for (int j = 0; j < 4; ++j)
                atomicAdd(&out[(size_t)m * R_ + n0 + 4 * tc + j], acc[i][j]);
        }
    }
}

// ---------------------------------------------------------------------------
// G1b: cmp_pe = window(k_pe) @ W_cmp_kpe   (unchanged)
// ---------------------------------------------------------------------------
__global__ __launch_bounds__(256) void g1b_cmppe(const float* __restrict__ A,
                                                 const float* __restrict__ W,
                                                 float* __restrict__ out) {
    const int t = threadIdx.x;
    const int m = blockIdx.x * 4 + (t >> 6);
    const int col = t & 63;
    if (m >= 510) return;
    const int b = (m >= NBLK) ? 1 : 0;
    const int n = m - b * NBLK;
    const float* arow = A + (size_t)(b * S_ + n * STRW) * ROPE;
    float acc = 0.f;
    for (int k = 0; k < 2048; k += 4) {
        float4 a4 = *(const float4*)(arow + k);
        acc = fmaf(a4.x, W[(size_t)(k + 0) * 64 + col], acc);
        acc = fmaf(a4.y, W[(size_t)(k + 1) * 64 + col], acc);
        acc = fmaf(a4.z, W[(size_t)(k + 2) * 64 + col], acc);
        acc = fmaf(a4.w, W[(size_t)(k + 3) * 64 + col], acc);
    }
    out[(size_t)m * 64 + col] = acc;
}

// ---------------------------------------------------------------------------
// G2: kvb = cmp_kv @ W_kv_b; epilogue writes K as 2 fp16 planes (h/l split)
// kh/kl [bh][n][192] and vT fp16 [bh][j][256] (col n=255 zeroed by memset).
// ---------------------------------------------------------------------------
__global__ __launch_bounds__(256) void g2_kvb(const float* __restrict__ A,
                                              const float* __restrict__ W,
                                              unsigned short* __restrict__ kh_g,
                                              unsigned short* __restrict__ kl_g,
                                              unsigned short* __restrict__ vT_g) {
    __shared__ float As[16][68];
    __shared__ float Bs[16][68];
    const int t  = threadIdx.x;
    const int m0 = blockIdx.x * 64;
    const int n0 = blockIdx.y * 64;
    const int tr = t >> 4, tc = t & 15;
    float acc[4][4];
#pragma unroll
    for (int i = 0; i < 4; ++i)
#pragma unroll
        for (int j = 0; j < 4; ++j) acc[i][j] = 0.f;

    for (int kt = 0; kt < R_; kt += 16) {
        __syncthreads();
        {
            int r = t >> 2, kq = (t & 3) * 4;
            int m = m0 + r;
            float4 av = make_float4(0.f, 0.f, 0.f, 0.f);
            if (m < 510) av = *(const float4*)(A + (size_t)m * R_ + kt + kq);
            As[kq + 0][r] = av.x; As[kq + 1][r] = av.y;
            As[kq + 2][r] = av.z; As[kq + 3][r] = av.w;
        }
        {
            int kb = t >> 4, nq = (t & 15) * 4;
            *(float4*)&Bs[kb][nq] =
                *(const float4*)(W + (size_t)(kt + kb) * 4096 + n0 + nq);
        }
        __syncthreads();
#pragma unroll
        for (int kk = 0; kk < 16; ++kk) {
            float4 x = *(const float4*)&As[kk][4 * tr];
            float4 z = *(const float4*)&Bs[kk][4 * tc];
            float a0[4] = {x.x, x.y, x.z, x.w};
            float b0[4] = {z.x, z.y, z.z, z.w};
#pragma unroll
            for (int i = 0; i < 4; ++i)
#pragma unroll
                for (int j = 0; j < 4; ++j)
                    acc[i][j] = fmaf(a0[i], b0[j], acc[i][j]);
        }
    }
#pragma unroll
    for (int i = 0; i < 4; ++i) {
        int m = m0 + 4 * tr + i;
        if (m < 510) {
            int b = (m >= NBLK) ? 1 : 0;
            int n = m - b * NBLK;
#pragma unroll
            for (int j = 0; j < 4; ++j) {
                int c = n0 + 4 * tc + j;
                int h = c >> 8, jj = c & 255;
                size_t bh = (size_t)(b * H_ + h);
                float x = acc[i][j];
                if (jj < NOPE) {
                    size_t idx = (bh * NBLK + n) * QKD + jj;
                    unsigned short uh, ul;
                    split2h(x, uh, ul);
                    kh_g[idx] = uh; kl_g[idx] = ul;
                } else {
                    vT_g[(bh * VD + (jj - NOPE)) * 256 + n] = f2h(x);
                }
            }
        }
    }
}

// G2b: rope part into K planes (d = 128..191), split2 per element.
__global__ void g2b_pefill(const float* __restrict__ cmp_pe,
                           unsigned short* __restrict__ kh_g,
                           unsigned short* __restrict__ kl_g) {
    int gid = blockIdx.x * 256 + threadIdx.x;   // 522240 total, exact
    int rr = gid & 63;
    int rest = gid >> 6;
    int n = rest % NBLK;
    int bh = rest / NBLK;
    int b = bh >> 4;
    float x = cmp_pe[((size_t)(b * NBLK + n)) * ROPE + rr];
    size_t idx = ((size_t)bh * NBLK + n) * QKD + NOPE + rr;
    unsigned short uh, ul;
    split2h(x, uh, ul);
    kh_g[idx] = uh; kl_g[idx] = ul;
}

// ---------------------------------------------------------------------------
// G3 v8: v6 arithmetic BIT-IDENTICAL; V staged in four 64-k quarters
// ([128][72] = 18,432 B) instead of two 128-k halves, shrinking peak LDS
// 68,608 -> 52,224 B => 3 blocks/CU (24 waves) instead of 2.
// Per (b,h, 64-row tile), 512 threads (8 waves), grid (64, 32).
// Score: fp16 2-way split, 3-term MFMA.  Softmax via 1KB rowred.
// probs: scb fp16 [64][264] + fp32 plane stores (plane mode, no atomics).
// ---------------------------------------------------------------------------
__global__ __launch_bounds__(512, 4) void g3_attn(const float* __restrict__ q,
                                               const unsigned short* __restrict__ kh_g,
                                               const unsigned short* __restrict__ kl_g,
                                               const unsigned short* __restrict__ vT_g,
                                               float* __restrict__ o,
                                               unsigned int* __restrict__ p_agg,
                                               float* __restrict__ ph_g) {
    __shared__ __attribute__((aligned(16))) char smem[52224];
    unsigned short* ksth = (unsigned short*)smem;            // [64][196]
    unsigned short* kstl = ksth + 12544;                     // [64][196]
    float* rowred       = (float*)(smem + 50176);            // [2][2][4][16] (1KB)
    unsigned short* scb = (unsigned short*)smem;             // [64][264] (overlays kst)
    unsigned short* vTl = (unsigned short*)(smem + 33792);   // [128][72] quarter

    const int t  = threadIdx.x;
    const int s0 = blockIdx.x * 64;
    const int bh = blockIdx.y;
    const int b = bh >> 4, h = bh & 15;
    const int wv = t >> 6, lane = t & 63;
    const int ln = lane & 15, quad = lane >> 4;
    const int mt = wv & 3, nhalf = wv >> 2;

    // ---- Q fragments: direct global load + fp16 2-way split into registers ----
    h8_t qfh[6], qfl[6];
    {
        const float* qrow = q + ((size_t)(b * S_ + s0 + 16 * mt + ln) * H_ + h) * QKD;
#pragma unroll
        for (int kk = 0; kk < 6; ++kk) {
            float4 x0 = *(const float4*)(qrow + kk * 32 + quad * 8);
            float4 x1 = *(const float4*)(qrow + kk * 32 + quad * 8 + 4);
            float v[8] = {x0.x, x0.y, x0.z, x0.w, x1.x, x1.y, x1.z, x1.w};
#pragma unroll
            for (int j = 0; j < 8; ++j) {
                _Float16 hh = (_Float16)v[j];
                qfh[kk][j] = hh;
                qfl[kk][j] = (_Float16)(v[j] - (float)hh);
            }
        }
    }

    // ---- score accumulators in registers: accs[chunk][ntile] ----
    f4_t accs[4][2];
#pragma unroll
    for (int c = 0; c < 4; ++c)
#pragma unroll
        for (int i = 0; i < 2; ++i) accs[c][i] = (f4_t){0.f, 0.f, 0.f, 0.f};

#pragma unroll
    for (int c = 0; c < 4; ++c) {
        // stage K chunk: 64 rows x 192 x 2 planes
#pragma unroll
        for (int u = 0; u < 6; ++u) {
            int f = t + u * 512;
            int p = f / 1536, rem = f % 1536;
            int row = rem / 24, sg = rem % 24;
            int gn = c * 64 + row;
            uint4 val = make_uint4(0, 0, 0, 0);
            const unsigned short* src = p ? kl_g : kh_g;
            if (gn < NBLK)
                val = *(const uint4*)(src + ((size_t)bh * NBLK + gn) * QKD + sg * 8);
            *(uint4*)((p ? kstl : ksth) + row * 196 + sg * 8) = val;
        }
        __syncthreads();
#pragma unroll
        for (int kk = 0; kk < 6; ++kk) {
#pragma unroll
            for (int i = 0; i < 2; ++i) {
                const unsigned short* bb = (nhalf * 32 + i * 16 + ln) * 196 + kk * 32 + quad * 8 + ksth;
                h8_t bhf = *(const h8_t*)bb;
                h8_t blf = *(const h8_t*)(bb + 12544);
                accs[c][i] = MFH(qfh[kk], bhf, accs[c][i]);
                accs[c][i] = MFH(qfh[kk], blf, accs[c][i]);
                accs[c][i] = MFH(qfl[kk], bhf, accs[c][i]);
            }
        }
        __syncthreads();   // readers done before next chunk restage
    }

    // ---- in-register masked softmax over each wave's 16 rows x 128 cols ----
    int nv[4];
    float mrow[4], srow[4], inv[4];
#pragma unroll
    for (int r = 0; r < 4; ++r) {
        int s = s0 + 16 * mt + quad * 4 + r;
        nv[r] = (s >= 31) ? (((s - 31) >> 4) + 1) : 0;
        mrow[r] = -INFINITY;
    }
#pragma unroll
    for (int c = 0; c < 4; ++c)
#pragma unroll
        for (int i = 0; i < 2; ++i) {
            int col = c * 64 + nhalf * 32 + i * 16 + ln;
#pragma unroll
            for (int r = 0; r < 4; ++r) {
                float v = (col < nv[r]) ? accs[c][i][r] * SCALEF : -INFINITY;
                accs[c][i][r] = v;
                mrow[r] = fmaxf(mrow[r], v);
            }
        }
#pragma unroll
    for (int r = 0; r < 4; ++r) {
#pragma unroll
        for (int off = 1; off < 16; off <<= 1)
            mrow[r] = fmaxf(mrow[r], __shfl_xor(mrow[r], off, 64));
    }
    if (ln == 0) {
#pragma unroll
        for (int r = 0; r < 4; ++r)
            rowred[((0 * 2 + nhalf) * 4 + mt) * 16 + quad * 4 + r] = mrow[r];
    }
    __syncthreads();
#pragma unroll
    for (int r = 0; r < 4; ++r) {
        int ri = mt * 16 + quad * 4 + r;
        mrow[r] = fmaxf(rowred[(0 * 2 + 0) * 64 + ri], rowred[(0 * 2 + 1) * 64 + ri]);
        srow[r] = 0.f;
    }
#pragma unroll
    for (int c = 0; c < 4; ++c)
#pragma unroll
        for (int i = 0; i < 2; ++i) {
            int col = c * 64 + nhalf * 32 + i * 16 + ln;
#pragma unroll
            for (int r = 0; r < 4; ++r) {
                float e = (col < nv[r]) ? __expf(accs[c][i][r] - mrow[r]) : 0.f;
                accs[c][i][r] = e;
                srow[r] += e;
            }
        }
#pragma unroll
    for (int r = 0; r < 4; ++r) {
#pragma unroll
        for (int off = 1; off < 16; off <<= 1)
            srow[r] += __shfl_xor(srow[r], off, 64);
    }
    if (ln == 0) {
#pragma unroll
        for (int r = 0; r < 4; ++r)
            rowred[((1 * 2 + nhalf) * 4 + mt) * 16 + quad * 4 + r] = srow[r];
    }
    __syncthreads();
#pragma unroll
    for (int r = 0; r < 4; ++r) {
        int ri = mt * 16 + quad * 4 + r;
        float tot = rowred[(1 * 2 + 0) * 64 + ri] + rowred[(1 * 2 + 1) * 64 + ri];
        inv[r] = (tot > 0.f) ? (1.0f / tot) : 0.f;
    }
    __syncthreads();   // rowred reads done; scb/vTl regions may be overwritten

    // ---- probs: scb fp16; fp32 plane store (plane mode) or atomicMax ----
#pragma unroll
    for (int c = 0; c < 4; ++c)
#pragma unroll
        for (int i = 0; i < 2; ++i) {
            int col = c * 64 + nhalf * 32 + i * 16 + ln;
#pragma unroll
            for (int r = 0; r < 4; ++r) {
                int row = 16 * mt + quad * 4 + r;
                float p = accs[c][i][r] * inv[r];
                scb[row * 264 + col] = f2h(p);
                if (ph_g != nullptr) {
                    ph_g[((size_t)bh * S_ + (s0 + row)) * 256 + col] = p;
                } else if (col < nv[r]) {
                    atomicMax(&p_agg[((size_t)(b * S_ + s0 + row)) * NBLK + col],
                              __float_as_uint(p));
                }
            }
        }

    // ---- PV: O(64x128) = P(64x256) @ V, four 64-k quarters ----
    const int mt2 = wv & 3, jgrp = wv >> 2;
    f4_t oacc[4];
#pragma unroll
    for (int jj = 0; jj < 4; ++jj) oacc[jj] = (f4_t){0.f, 0.f, 0.f, 0.f};
#pragma unroll
    for (int kq = 0; kq < 4; ++kq) {
        __syncthreads();   // scb writes (kq=0) / prior quarter's MFMA reads done
#pragma unroll
        for (int u = 0; u < 2; ++u) {
            int f = t + u * 512;
            int j = f >> 3, sg = f & 7;
            *(uint4*)(vTl + j * 72 + sg * 8) =
                *(const uint4*)(vT_g + ((size_t)bh * VD + j) * 256 + kq * 64 + sg * 8);
        }
        __syncthreads();
#pragma unroll
        for (int kk = 0; kk < 2; ++kk) {
            h8_t pf = *(const h8_t*)(scb + (16 * mt2 + ln) * 264 + kq * 64 + kk * 32 + quad * 8);
#pragma unroll
            for (int jj = 0; jj < 4; ++jj) {
                h8_t vf = *(const h8_t*)(vTl + ((jgrp * 4 + jj) * 16 + ln) * 72 + kk * 32 + quad * 8);
                oacc[jj] = MFH(pf, vf, oacc[jj]);
            }
        }
    }
#pragma unroll
    for (int jj = 0; jj < 4; ++jj) {
#pragma unroll
        for (int r = 0; r < 4; ++r) {
            int row = 16 * mt2 + quad * 4 + r;
            o[((size_t)(b * S_ + s0 + row)) * 2048 + h * VD + (jgrp * 4 + jj) * 16 + ln] =
                oacc[jj][r];
        }
    }
}

// ---------------------------------------------------------------------------
// G3b: p_agg[b][s][n] = max over 16 heads of fp32 prob planes.  (unchanged)
// ---------------------------------------------------------------------------
__global__ __launch_bounds__(256) void g3b_pmax(const float* __restrict__ ph,
                                                float* __restrict__ p_agg) {
    int tid = blockIdx.x * 256 + threadIdx.x;   // w*256 + n
    int n = tid & 255;
    int w = tid >> 8;                           // = b*S + s
    if (n >= NBLK) return;
    int b = w >> 12;
    int s = w & (S_ - 1);
    const float* base = ph + ((size_t)(b * H_) * S_ + s) * 256 + n;
    float m = 0.f;
#pragma unroll
    for (int hh = 0; hh < H_; ++hh)
        m = fmaxf(m, base[(size_t)hh * S_ * 256]);
    p_agg[(size_t)w * NBLK + n] = m;
}

// ---------------------------------------------------------------------------
// G4: slc + forced/causal + top-16.  (unchanged)
// ---------------------------------------------------------------------------
__global__ __launch_bounds__(256) void g4_topk(const float* __restrict__ p_agg,
                                               float* __restrict__ outI) {
    const int gid  = blockIdx.x * 256 + threadIdx.x;
    const int w    = gid >> 6;          // = b*S + s
    const int lane = threadIdx.x & 63;  // = j
    const int s    = w & (S_ - 1);
    const float* pa = p_agg + (size_t)w * NBLK;
    const int j = lane;
    float slc = 0.f;
    int nlo = 4 * j - 1; if (nlo < 0) nlo = 0;
    int nhi = 4 * j + 3; if (nhi > NBLK - 1) nhi = NBLK - 1;
    for (int n = nlo; n <= nhi; ++n) slc += pa[n];
    const int jt = s >> 6;
    float val;
    if (j <= jt) val = ((j < 1) || (j >= jt - 1)) ? BIGF : slc;
    else         val = -BIGF;
    bool taken = false;
    float* dst = outI + (size_t)w * TOPKN;
    for (int kk = 0; kk < TOPKN; ++kk) {
        float v = taken ? -INFINITY : val;
        float m = v;
#pragma unroll
        for (int off = 32; off; off >>= 1) m = fmaxf(m, __shfl_xor(m, off, 64));
        unsigned long long msk = __ballot((!taken) && (val == m));
        int first = __ffsll(msk) - 1;
        if (lane == first) taken = true;
        if (lane == kk) dst[kk] = (m <= -BIGF * 0.5f) ? -1.0f : (float)first;
    }
}

// ---------------------------------------------------------------------------
extern "C" void kernel_launch(void* const* d_in, const int* in_sizes, int n_in,
                              void* d_out, int out_size, void* d_ws, size_t ws_size,
                              hipStream_t stream) {
    const float* q         = (const float*)d_in[0];
    const float* kv_lora   = (const float*)d_in[1];
    const float* k_pe      = (const float*)d_in[2];
    const float* W_cmp_kv  = (const float*)d_in[3];
    const float* W_cmp_kpe = (const float*)d_in[4];
    const float* W_kv_b    = (const float*)d_in[5];
    float* out = (float*)d_out;
    char* W = (char*)d_ws;

    // byte offsets (all 16-aligned)
    float* cmp_kv        = (float*)W;                         // 1,044,480 B
    float* cmp_pe        = (float*)(W + 1044480);             //   130,560 B
    unsigned int* p_agg  = (unsigned int*)(W + 1175040);      // 8,355,840 B
    unsigned short* kh_g = (unsigned short*)(W + 9530880);    // 3,133,440 B
    unsigned short* kl_g = (unsigned short*)(W + 12664320);   // 3,133,440 B
    unsigned short* vT_g = (unsigned short*)(W + 15797760);   // 2,097,152 B
    float* ph            = (float*)(W + 17894912);            // 134,217,728 B
                                                              // end 152,112,640 B
    const bool plane = (ws_size >= (size_t)152112640);
    float* ph_arg = plane ? ph : nullptr;

    hipMemsetAsync(cmp_kv, 0, (size_t)1044480, stream);
    if (!plane) hipMemsetAsync(p_agg, 0, (size_t)8355840, stream);
    hipMemsetAsync(vT_g, 0, (size_t)2097152, stream);   // n=255 column stays 0.0

    g1_cmpkv  <<<dim3(4, 8, 16), 256, 0, stream>>>(kv_lora, W_cmp_kv, cmp_kv);
    g1b_cmppe <<<dim3(128),      256, 0, stream>>>(k_pe, W_cmp_kpe, cmp_pe);
    g2_kvb    <<<dim3(8, 64),    256, 0, stream>>>(cmp_kv, W_kv_b, kh_g, kl_g, vT_g);
    g2b_pefill<<<dim3(2040),     256, 0, stream>>>(cmp_pe, kh_g, kl_g);
    g3_attn   <<<dim3(64, 32),   512, 0, stream>>>(q, kh_g, kl_g, vT_g, out, p_agg,
                                                   ph_arg);
    if (plane)
        g3b_pmax <<<dim3(8192),  256, 0, stream>>>(ph, (float*)p_agg);
    g4_topk   <<<dim3(2048),     256, 0, stream>>>((const float*)p_agg, out + 16777216);
}

// Round 7
// 633.231 us; speedup vs baseline: 1.2103x; 1.2103x over previous
//
#include <hip/hip_runtime.h>
#include <hip/hip_bf16.h>
#include <stdint.h>

#define B_    2
#define S_    4096
#define H_    16
#define NOPE  128
#define ROPE  64
#define QKD   192
#define VD    128
#define R_    512
#define STRW  16
#define NBLK  255
#define TOPKN 16
#define SCALEF 0.07216878364870323f
#define BIGF   1000000000.0f
#define WSCALE 1024.0f
#define WINV   (1.0f / 1024.0f)

typedef __attribute__((ext_vector_type(8))) _Float16 h8_t;   // 8 fp16 (4 VGPRs)
typedef __attribute__((ext_vector_type(4))) float f4_t;      // MFMA acc

#define MFH(a,b,c) __builtin_amdgcn_mfma_f32_16x16x32_f16((a),(b),(c),0,0,0)

__device__ inline unsigned short f2h(float x) {
    _Float16 hh = (_Float16)x;
    return *(unsigned short*)&hh;
}
// 2-way fp16 split: x ~= h + l, residual ~2^-22 rel
__device__ inline void split2h(float x, unsigned short& h, unsigned short& l) {
    _Float16 hh = (_Float16)x;
    _Float16 ll = (_Float16)(x - (float)hh);
    h = *(unsigned short*)&hh;
    l = *(unsigned short*)&ll;
}

// ---------------------------------------------------------------------------
// G0a: split kv_lora (2*4096*512 fp32) into fp16 h/l planes (unscaled; O(1)).
// ---------------------------------------------------------------------------
__global__ __launch_bounds__(256) void g0_kvsplit(const float* __restrict__ kv,
                                                  unsigned short* __restrict__ kvh,
                                                  unsigned short* __restrict__ kvl) {
    int gid = blockIdx.x * 256 + threadIdx.x;   // 524288 total, exact
    size_t base = (size_t)gid * 8;
    float4 a = *(const float4*)(kv + base);
    float4 b = *(const float4*)(kv + base + 4);
    float v[8] = {a.x, a.y, a.z, a.w, b.x, b.y, b.z, b.w};
    unsigned short uh[8] __attribute__((aligned(16)));
    unsigned short ul[8] __attribute__((aligned(16)));
#pragma unroll
    for (int j = 0; j < 8; ++j) split2h(v[j], uh[j], ul[j]);
    *(uint4*)(kvh + base) = *(const uint4*)uh;
    *(uint4*)(kvl + base) = *(const uint4*)ul;
}

// ---------------------------------------------------------------------------
// G0b: transpose+split W_cmp_kv [16384][512] -> Wth/Wtl [512][16384] fp16,
// PRE-SCALED by 2^10: W ~ 0.008 makes the raw fp16 low plane subnormal
// (< 6.1e-5) which the matrix pipe flushes (v7 failure).  Scaled planes are
// normal; epilogue multiplies by 2^-10 (exact).
// ---------------------------------------------------------------------------
__global__ __launch_bounds__(256) void g0_wtsplit(const float* __restrict__ Wsrc,
                                                  unsigned short* __restrict__ Wth,
                                                  unsigned short* __restrict__ Wtl) {
    __shared__ float Ls[64][65];
    const int t = threadIdx.x;
    const int k0 = blockIdx.x * 64, n0 = blockIdx.y * 64;
    {
        int r = t >> 2, c0 = (t & 3) * 16;
#pragma unroll
        for (int j = 0; j < 4; ++j) {
            float4 v = *(const float4*)(Wsrc + (size_t)(k0 + r) * 512 + n0 + c0 + j * 4);
            Ls[r][c0 + j * 4 + 0] = v.x; Ls[r][c0 + j * 4 + 1] = v.y;
            Ls[r][c0 + j * 4 + 2] = v.z; Ls[r][c0 + j * 4 + 3] = v.w;
        }
    }
    __syncthreads();
    {
        int nrow = t >> 2, seg = t & 3;
        unsigned short uh[16] __attribute__((aligned(16)));
        unsigned short ul[16] __attribute__((aligned(16)));
#pragma unroll
        for (int j = 0; j < 16; ++j)
            split2h(Ls[seg * 16 + j][nrow] * WSCALE, uh[j], ul[j]);
        size_t dst = (size_t)(n0 + nrow) * 16384 + k0 + seg * 16;
        *(uint4*)(Wth + dst)     = ((const uint4*)uh)[0];
        *(uint4*)(Wth + dst + 8) = ((const uint4*)uh)[1];
        *(uint4*)(Wtl + dst)     = ((const uint4*)ul)[0];
        *(uint4*)(Wtl + dst + 8) = ((const uint4*)ul)[1];
    }
}

// ---------------------------------------------------------------------------
// G1-MFMA: cmp_kv = window(kv_lora) @ W_cmp_kv via fp16-split 3-term MFMA.
// M=512(510 valid) x N=512 x K=16384.  Tile 128x64, split-K=8 (K=2048/block),
// grid (4,8,8)=256 blocks (1/CU), 512 thr (8 waves = 4mt x 2nh, 32x32/wave).
// Double-buffered LDS (104448 B).  Epilogue: fp32 atomicAdd x WINV descale.
// ---------------------------------------------------------------------------
__global__ __launch_bounds__(512, 2) void g1_mfma(const unsigned short* __restrict__ kvh,
                                                  const unsigned short* __restrict__ kvl,
                                                  const unsigned short* __restrict__ Wth,
                                                  const unsigned short* __restrict__ Wtl,
                                                  float* __restrict__ out) {
    __shared__ __attribute__((aligned(16))) unsigned short Abuf[2][2][128][68];
    __shared__ __attribute__((aligned(16))) unsigned short Bbuf[2][2][64][68];
    const int t  = threadIdx.x;
    const int m0 = blockIdx.x * 128;
    const int n0 = blockIdx.y * 64;
    const int k0 = blockIdx.z * 2048;
    const int wv = t >> 6, lane = t & 63;
    const int ln = lane & 15, quad = lane >> 4;
    const int mt = wv & 3, nh = wv >> 2;

    f4_t acc[2][2];
#pragma unroll
    for (int i = 0; i < 2; ++i)
#pragma unroll
        for (int j = 0; j < 2; ++j) acc[i][j] = (f4_t){0.f, 0.f, 0.f, 0.f};

    auto stage = [&](int c, int bufi) {
        int gk = k0 + c * 64;
        int w = gk >> 9, rr = gk & 511;
        // A: 128 rows x 64 k x 2 planes = 2048 uint4
#pragma unroll
        for (int u = 0; u < 4; ++u) {
            int f = t + u * 512;
            int p = f >> 10, rem = f & 1023;
            int row = rem >> 3, sg = rem & 7;
            int m = m0 + row;
            uint4 val = make_uint4(0, 0, 0, 0);
            if (m < 510) {
                int b = (m >= NBLK) ? 1 : 0;
                int n = m - b * NBLK;
                const unsigned short* src = p ? kvl : kvh;
                val = *(const uint4*)(src + (size_t)(b * S_ + n * STRW + w) * R_ + rr + sg * 8);
            }
            *(uint4*)&Abuf[bufi][p][row][sg * 8] = val;
        }
        // B: 64 n-rows x 64 k x 2 planes = 1024 uint4
#pragma unroll
        for (int u = 0; u < 2; ++u) {
            int f = t + u * 512;
            int p = f >> 9, rem = f & 511;
            int nrow = rem >> 3, sg = rem & 7;
            const unsigned short* src = p ? Wtl : Wth;
            uint4 val = *(const uint4*)(src + (size_t)(n0 + nrow) * 16384 + gk + sg * 8);
            *(uint4*)&Bbuf[bufi][p][nrow][sg * 8] = val;
        }
    };
    auto compute = [&](int bufi) {
#pragma unroll
        for (int ks = 0; ks < 2; ++ks) {
#pragma unroll
            for (int iA = 0; iA < 2; ++iA) {
                h8_t ah = *(const h8_t*)&Abuf[bufi][0][mt * 32 + iA * 16 + ln][ks * 32 + quad * 8];
                h8_t al = *(const h8_t*)&Abuf[bufi][1][mt * 32 + iA * 16 + ln][ks * 32 + quad * 8];
#pragma unroll
                for (int jB = 0; jB < 2; ++jB) {
                    h8_t bh = *(const h8_t*)&Bbuf[bufi][0][nh * 32 + jB * 16 + ln][ks * 32 + quad * 8];
                    h8_t bl = *(const h8_t*)&Bbuf[bufi][1][nh * 32 + jB * 16 + ln][ks * 32 + quad * 8];
                    acc[iA][jB] = MFH(ah, bh, acc[iA][jB]);
                    acc[iA][jB] = MFH(ah, bl, acc[iA][jB]);
                    acc[iA][jB] = MFH(al, bh, acc[iA][jB]);
                }
            }
        }
    };

    stage(0, 0);
    __syncthreads();
    for (int c = 0; c < 32; ++c) {
        if (c + 1 < 32) stage(c + 1, (c + 1) & 1);
        compute(c & 1);
        __syncthreads();
    }
#pragma unroll
    for (int iA = 0; iA < 2; ++iA)
#pragma unroll
        for (int jB = 0; jB < 2; ++jB)
#pragma unroll
            for (int r = 0; r < 4; ++r) {
                int m = m0 + mt * 32 + iA * 16 + quad * 4 + r;
                if (m < 510)
                    atomicAdd(&out[(size_t)m * R_ + n0 + nh * 32 + jB * 16 + ln],
                              acc[iA][jB][r] * WINV);
            }
}

// ---------------------------------------------------------------------------
// G1: legacy fp32 path (fallback when workspace too small for planes).
// ---------------------------------------------------------------------------
__global__ __launch_bounds__(256) void g1_cmpkv(const float* __restrict__ A,
                                                const float* __restrict__ W,
                                                float* __restrict__ out) {
    __shared__ float As[16][132];
    __shared__ float Bs[16][68];
    const int t  = threadIdx.x;
    const int m0 = blockIdx.x * 128;
    const int n0 = blockIdx.y * 64;
    const int k0 = blockIdx.z * 1024;
    const int tr = t >> 4, tc = t & 15;
    float acc[8][4];
#pragma unroll
    for (int i = 0; i < 8; ++i)
#pragma unroll
        for (int j = 0; j < 4; ++j) acc[i][j] = 0.f;

    for (int kt = 0; kt < 1024; kt += 16) {
        __syncthreads();
#pragma unroll
        for (int i = 0; i < 2; ++i) {
            int f = t + i * 256;
            int r = f >> 2, kq = (f & 3) * 4;
            int m = m0 + r;
            float4 av = make_float4(0.f, 0.f, 0.f, 0.f);
            if (m < 510) {
                int b = (m >= NBLK) ? 1 : 0;
                int n = m - b * NBLK;
                av = *(const float4*)(A + (size_t)(b * S_ + n * STRW) * R_ + k0 + kt + kq);
            }
            As[kq + 0][r] = av.x; As[kq + 1][r] = av.y;
            As[kq + 2][r] = av.z; As[kq + 3][r] = av.w;
        }
        {
            int kb = t >> 4, nq = (t & 15) * 4;
            *(float4*)&Bs[kb][nq] =
                *(const float4*)(W + (size_t)(k0 + kt + kb) * R_ + n0 + nq);
        }
        __syncthreads();
#pragma unroll
        for (int kk = 0; kk < 16; ++kk) {
            float a0[8], b0[4];
            float4 x = *(const float4*)&As[kk][8 * tr];
            float4 y = *(const float4*)&As[kk][8 * tr + 4];
            a0[0] = x.x; a0[1] = x.y; a0[2] = x.z; a0[3] = x.w;
            a0[4] = y.x; a0[5] = y.y; a0[6] = y.z; a0[7] = y.w;
            float4 z = *(const float4*)&Bs[kk][4 * tc];
            b0[0] = z.x; b0[1] = z.y; b0[2] = z.z; b0[3] = z.w;
#pragma unroll
            for (int i = 0; i < 8; ++i)
#pragma unroll
                for (int j = 0; j < 4; ++j)
                    acc[i][j] = fmaf(a0[i], b0[j], acc[i][j]);
        }
    }
#pragma unroll
    for (int i = 0; i < 8; ++i) {
        int m = m0 + 8 * tr + i;
        if (m < 510) {
#pragma unroll
            for (int j = 0; j < 4; ++j)
                atomicAdd(&out[(size_t)m * R_ + n0 + 4 * tc + j], acc[i][j]);
        }
    }
}

// ---------------------------------------------------------------------------
// G1b v2: cmp_pe = window(k_pe) @ W_cmp_kpe.  One block per output row m
// (510 blocks, 2/CU), 256 thr: col = t&63, K-quarter = t>>6 (512 k each),
// 4 independent fma chains per thread, LDS cross-quarter reduce.
// (was: 128 blocks = 0.5/CU, single 8192-deep fma chain)
// ---------------------------------------------------------------------------
__global__ __launch_bounds__(256) void g1b_cmppe(const float* __restrict__ A,
                                                 const float* __restrict__ W,
                                                 float* __restrict__ out) {
    __shared__ float red[4][64];
    const int t = threadIdx.x;
    const int m = blockIdx.x;
    const int col = t & 63, kc = t >> 6;
    const int b = (m >= NBLK) ? 1 : 0;
    const int n = m - b * NBLK;
    const float* arow = A + (size_t)(b * S_ + n * STRW) * ROPE + kc * 512;
    const float* wcol = W + (size_t)kc * 512 * 64 + col;
    float a0 = 0.f, a1 = 0.f, a2 = 0.f, a3 = 0.f;
    for (int k = 0; k < 512; k += 4) {
        float4 a4 = *(const float4*)(arow + k);
        a0 = fmaf(a4.x, wcol[(size_t)(k + 0) * 64], a0);
        a1 = fmaf(a4.y, wcol[(size_t)(k + 1) * 64], a1);
        a2 = fmaf(a4.z, wcol[(size_t)(k + 2) * 64], a2);
        a3 = fmaf(a4.w, wcol[(size_t)(k + 3) * 64], a3);
    }
    red[kc][col] = ((a0 + a1) + (a2 + a3));
    __syncthreads();
    if (kc == 0)
        out[(size_t)m * 64 + col] =
            (red[0][col] + red[1][col]) + (red[2][col] + red[3][col]);
}

// ---------------------------------------------------------------------------
// G2: kvb = cmp_kv @ W_kv_b; epilogue writes K as 2 fp16 planes (h/l split)
// kh/kl [bh][n][192] and vT fp16 [bh][j][256] (col n=255 zeroed by memset).
// ---------------------------------------------------------------------------
__global__ __launch_bounds__(256) void g2_kvb(const float* __restrict__ A,
                                              const float* __restrict__ W,
                                              unsigned short* __restrict__ kh_g,
                                              unsigned short* __restrict__ kl_g,
                                              unsigned short* __restrict__ vT_g) {
    __shared__ float As[16][68];
    __shared__ float Bs[16][68];
    const int t  = threadIdx.x;
    const int m0 = blockIdx.x * 64;
    const int n0 = blockIdx.y * 64;
    const int tr = t >> 4, tc = t & 15;
    float acc[4][4];
#pragma unroll
    for (int i = 0; i < 4; ++i)
#pragma unroll
        for (int j = 0; j < 4; ++j) acc[i][j] = 0.f;

    for (int kt = 0; kt < R_; kt += 16) {
        __syncthreads();
        {
            int r = t >> 2, kq = (t & 3) * 4;
            int m = m0 + r;
            float4 av = make_float4(0.f, 0.f, 0.f, 0.f);
            if (m < 510) av = *(const float4*)(A + (size_t)m * R_ + kt + kq);
            As[kq + 0][r] = av.x; As[kq + 1][r] = av.y;
            As[kq + 2][r] = av.z; As[kq + 3][r] = av.w;
        }
        {
            int kb = t >> 4, nq = (t & 15) * 4;
            *(float4*)&Bs[kb][nq] =
                *(const float4*)(W + (size_t)(kt + kb) * 4096 + n0 + nq);
        }
        __syncthreads();
#pragma unroll
        for (int kk = 0; kk < 16; ++kk) {
            float4 x = *(const float4*)&As[kk][4 * tr];
            float4 z = *(const float4*)&Bs[kk][4 * tc];
            float a0[4] = {x.x, x.y, x.z, x.w};
            float b0[4] = {z.x, z.y, z.z, z.w};
#pragma unroll
            for (int i = 0; i < 4; ++i)
#pragma unroll
                for (int j = 0; j < 4; ++j)
                    acc[i][j] = fmaf(a0[i], b0[j], acc[i][j]);
        }
    }
#pragma unroll
    for (int i = 0; i < 4; ++i) {
        int m = m0 + 4 * tr + i;
        if (m < 510) {
            int b = (m >= NBLK) ? 1 : 0;
            int n = m - b * NBLK;
#pragma unroll
            for (int j = 0; j < 4; ++j) {
                int c = n0 + 4 * tc + j;
                int h = c >> 8, jj = c & 255;
                size_t bh = (size_t)(b * H_ + h);
                float x = acc[i][j];
                if (jj < NOPE) {
                    size_t idx = (bh * NBLK + n) * QKD + jj;
                    unsigned short uh, ul;
                    split2h(x, uh, ul);
                    kh_g[idx] = uh; kl_g[idx] = ul;
                } else {
                    vT_g[(bh * VD + (jj - NOPE)) * 256 + n] = f2h(x);
                }
            }
        }
    }
}

// G2b: rope part into K planes (d = 128..191), split2 per element.
__global__ void g2b_pefill(const float* __restrict__ cmp_pe,
                           unsigned short* __restrict__ kh_g,
                           unsigned short* __restrict__ kl_g) {
    int gid = blockIdx.x * 256 + threadIdx.x;   // 522240 total, exact
    int rr = gid & 63;
    int rest = gid >> 6;
    int n = rest % NBLK;
    int bh = rest / NBLK;
    int b = bh >> 4;
    float x = cmp_pe[((size_t)(b * NBLK + n)) * ROPE + rr];
    size_t idx = ((size_t)bh * NBLK + n) * QKD + NOPE + rr;
    unsigned short uh, ul;
    split2h(x, uh, ul);
    kh_g[idx] = uh; kl_g[idx] = ul;
}

// ---------------------------------------------------------------------------
// G3 v8: UNCHANGED from round 6 (passing, 273 us).
// ---------------------------------------------------------------------------
__global__ __launch_bounds__(512, 4) void g3_attn(const float* __restrict__ q,
                                               const unsigned short* __restrict__ kh_g,
                                               const unsigned short* __restrict__ kl_g,
                                               const unsigned short* __restrict__ vT_g,
                                               float* __restrict__ o,
                                               unsigned int* __restrict__ p_agg,
                                               float* __restrict__ ph_g) {
    __shared__ __attribute__((aligned(16))) char smem[52224];
    unsigned short* ksth = (unsigned short*)smem;            // [64][196]
    unsigned short* kstl = ksth + 12544;                     // [64][196]
    float* rowred       = (float*)(smem + 50176);            // [2][2][4][16] (1KB)
    unsigned short* scb = (unsigned short*)smem;             // [64][264] (overlays kst)
    unsigned short* vTl = (unsigned short*)(smem + 33792);   // [128][72] quarter

    const int t  = threadIdx.x;
    const int s0 = blockIdx.x * 64;
    const int bh = blockIdx.y;
    const int b = bh >> 4, h = bh & 15;
    const int wv = t >> 6, lane = t & 63;
    const int ln = lane & 15, quad = lane >> 4;
    const int mt = wv & 3, nhalf = wv >> 2;

    // ---- Q fragments: direct global load + fp16 2-way split into registers ----
    h8_t qfh[6], qfl[6];
    {
        const float* qrow = q + ((size_t)(b * S_ + s0 + 16 * mt + ln) * H_ + h) * QKD;
#pragma unroll
        for (int kk = 0; kk < 6; ++kk) {
            float4 x0 = *(const float4*)(qrow + kk * 32 + quad * 8);
            float4 x1 = *(const float4*)(qrow + kk * 32 + quad * 8 + 4);
            float v[8] = {x0.x, x0.y, x0.z, x0.w, x1.x, x1.y, x1.z, x1.w};
#pragma unroll
            for (int j = 0; j < 8; ++j) {
                _Float16 hh = (_Float16)v[j];
                qfh[kk][j] = hh;
                qfl[kk][j] = (_Float16)(v[j] - (float)hh);
            }
        }
    }

    // ---- score accumulators in registers: accs[chunk][ntile] ----
    f4_t accs[4][2];
#pragma unroll
    for (int c = 0; c < 4; ++c)
#pragma unroll
        for (int i = 0; i < 2; ++i) accs[c][i] = (f4_t){0.f, 0.f, 0.f, 0.f};

#pragma unroll
    for (int c = 0; c < 4; ++c) {
        // stage K chunk: 64 rows x 192 x 2 planes
#pragma unroll
        for (int u = 0; u < 6; ++u) {
            int f = t + u * 512;
            int p = f / 1536, rem = f % 1536;
            int row = rem / 24, sg = rem % 24;
            int gn = c * 64 + row;
            uint4 val = make_uint4(0, 0, 0, 0);
            const unsigned short* src = p ? kl_g : kh_g;
            if (gn < NBLK)
                val = *(const uint4*)(src + ((size_t)bh * NBLK + gn) * QKD + sg * 8);
            *(uint4*)((p ? kstl : ksth) + row * 196 + sg * 8) = val;
        }
        __syncthreads();
#pragma unroll
        for (int kk = 0; kk < 6; ++kk) {
#pragma unroll
            for (int i = 0; i < 2; ++i) {
                const unsigned short* bb = (nhalf * 32 + i * 16 + ln) * 196 + kk * 32 + quad * 8 + ksth;
                h8_t bhf = *(const h8_t*)bb;
                h8_t blf = *(const h8_t*)(bb + 12544);
                accs[c][i] = MFH(qfh[kk], bhf, accs[c][i]);
                accs[c][i] = MFH(qfh[kk], blf, accs[c][i]);
                accs[c][i] = MFH(qfl[kk], bhf, accs[c][i]);
            }
        }
        __syncthreads();   // readers done before next chunk restage
    }

    // ---- in-register masked softmax over each wave's 16 rows x 128 cols ----
    int nv[4];
    float mrow[4], srow[4], inv[4];
#pragma unroll
    for (int r = 0; r < 4; ++r) {
        int s = s0 + 16 * mt + quad * 4 + r;
        nv[r] = (s >= 31) ? (((s - 31) >> 4) + 1) : 0;
        mrow[r] = -INFINITY;
    }
#pragma unroll
    for (int c = 0; c < 4; ++c)
#pragma unroll
        for (int i = 0; i < 2; ++i) {
            int col = c * 64 + nhalf * 32 + i * 16 + ln;
#pragma unroll
            for (int r = 0; r < 4; ++r) {
                float v = (col < nv[r]) ? accs[c][i][r] * SCALEF : -INFINITY;
                accs[c][i][r] = v;
                mrow[r] = fmaxf(mrow[r], v);
            }
        }
#pragma unroll
    for (int r = 0; r < 4; ++r) {
#pragma unroll
        for (int off = 1; off < 16; off <<= 1)
            mrow[r] = fmaxf(mrow[r], __shfl_xor(mrow[r], off, 64));
    }
    if (ln == 0) {
#pragma unroll
        for (int r = 0; r < 4; ++r)
            rowred[((0 * 2 + nhalf) * 4 + mt) * 16 + quad * 4 + r] = mrow[r];
    }
    __syncthreads();
#pragma unroll
    for (int r = 0; r < 4; ++r) {
        int ri = mt * 16 + quad * 4 + r;
        mrow[r] = fmaxf(rowred[(0 * 2 + 0) * 64 + ri], rowred[(0 * 2 + 1) * 64 + ri]);
        srow[r] = 0.f;
    }
#pragma unroll
    for (int c = 0; c < 4; ++c)
#pragma unroll
        for (int i = 0; i < 2; ++i) {
            int col = c * 64 + nhalf * 32 + i * 16 + ln;
#pragma unroll
            for (int r = 0; r < 4; ++r) {
                float e = (col < nv[r]) ? __expf(accs[c][i][r] - mrow[r]) : 0.f;
                accs[c][i][r] = e;
                srow[r] += e;
            }
        }
#pragma unroll
    for (int r = 0; r < 4; ++r) {
#pragma unroll
        for (int off = 1; off < 16; off <<= 1)
            srow[r] += __shfl_xor(srow[r], off, 64);
    }
    if (ln == 0) {
#pragma unroll
        for (int r = 0; r < 4; ++r)
            rowred[((1 * 2 + nhalf) * 4 + mt) * 16 + quad * 4 + r] = srow[r];
    }
    __syncthreads();
#pragma unroll
    for (int r = 0; r < 4; ++r) {
        int ri = mt * 16 + quad * 4 + r;
        float tot = rowred[(1 * 2 + 0) * 64 + ri] + rowred[(1 * 2 + 1) * 64 + ri];
        inv[r] = (tot > 0.f) ? (1.0f / tot) : 0.f;
    }
    __syncthreads();   // rowred reads done; scb/vTl regions may be overwritten

    // ---- probs: scb fp16; fp32 plane store (plane mode) or atomicMax ----
#pragma unroll
    for (int c = 0; c < 4; ++c)
#pragma unroll
        for (int i = 0; i < 2; ++i) {
            int col = c * 64 + nhalf * 32 + i * 16 + ln;
#pragma unroll
            for (int r = 0; r < 4; ++r) {
                int row = 16 * mt + quad * 4 + r;
                float p = accs[c][i][r] * inv[r];
                scb[row * 264 + col] = f2h(p);
                if (ph_g != nullptr) {
                    ph_g[((size_t)bh * S_ + (s0 + row)) * 256 + col] = p;
                } else if (col < nv[r]) {
                    atomicMax(&p_agg[((size_t)(b * S_ + s0 + row)) * NBLK + col],
                              __float_as_uint(p));
                }
            }
        }

    // ---- PV: O(64x128) = P(64x256) @ V, four 64-k quarters ----
    const int mt2 = wv & 3, jgrp = wv >> 2;
    f4_t oacc[4];
#pragma unroll
    for (int jj = 0; jj < 4; ++jj) oacc[jj] = (f4_t){0.f, 0.f, 0.f, 0.f};
#pragma unroll
    for (int kq = 0; kq < 4; ++kq) {
        __syncthreads();   // scb writes (kq=0) / prior quarter's MFMA reads done
#pragma unroll
        for (int u = 0; u < 2; ++u) {
            int f = t + u * 512;
            int j = f >> 3, sg = f & 7;
            *(uint4*)(vTl + j * 72 + sg * 8) =
                *(const uint4*)(vT_g + ((size_t)bh * VD + j) * 256 + kq * 64 + sg * 8);
        }
        __syncthreads();
#pragma unroll
        for (int kk = 0; kk < 2; ++kk) {
            h8_t pf = *(const h8_t*)(scb + (16 * mt2 + ln) * 264 + kq * 64 + kk * 32 + quad * 8);
#pragma unroll
            for (int jj = 0; jj < 4; ++jj) {
                h8_t vf = *(const h8_t*)(vTl + ((jgrp * 4 + jj) * 16 + ln) * 72 + kk * 32 + quad * 8);
                oacc[jj] = MFH(pf, vf, oacc[jj]);
            }
        }
    }
#pragma unroll
    for (int jj = 0; jj < 4; ++jj) {
#pragma unroll
        for (int r = 0; r < 4; ++r) {
            int row = 16 * mt2 + quad * 4 + r;
            o[((size_t)(b * S_ + s0 + row)) * 2048 + h * VD + (jgrp * 4 + jj) * 16 + ln] =
                oacc[jj][r];
        }
    }
}

// ---------------------------------------------------------------------------
// G3b: p_agg[b][s][n] = max over 16 heads of fp32 prob planes.  (unchanged)
// ---------------------------------------------------------------------------
__global__ __launch_bounds__(256) void g3b_pmax(const float* __restrict__ ph,
                                                float* __restrict__ p_agg) {
    int tid = blockIdx.x * 256 + threadIdx.x;   // w*256 + n
    int n = tid & 255;
    int w = tid >> 8;                           // = b*S + s
    if (n >= NBLK) return;
    int b = w >> 12;
    int s = w & (S_ - 1);
    const float* base = ph + ((size_t)(b * H_) * S_ + s) * 256 + n;
    float m = 0.f;
#pragma unroll
    for (int hh = 0; hh < H_; ++hh)
        m = fmaxf(m, base[(size_t)hh * S_ * 256]);
    p_agg[(size_t)w * NBLK + n] = m;
}

// ---------------------------------------------------------------------------
// G4: slc + forced/causal + top-16.  (unchanged)
// ---------------------------------------------------------------------------
__global__ __launch_bounds__(256) void g4_topk(const float* __restrict__ p_agg,
                                               float* __restrict__ outI) {
    const int gid  = blockIdx.x * 256 + threadIdx.x;
    const int w    = gid >> 6;          // = b*S + s
    const int lane = threadIdx.x & 63;  // = j
    const int s    = w & (S_ - 1);
    const float* pa = p_agg + (size_t)w * NBLK;
    const int j = lane;
    float slc = 0.f;
    int nlo = 4 * j - 1; if (nlo < 0) nlo = 0;
    int nhi = 4 * j + 3; if (nhi > NBLK - 1) nhi = NBLK - 1;
    for (int n = nlo; n <= nhi; ++n) slc += pa[n];
    const int jt = s >> 6;
    float val;
    if (j <= jt) val = ((j < 1) || (j >= jt - 1)) ? BIGF : slc;
    else         val = -BIGF;
    bool taken = false;
    float* dst = outI + (size_t)w * TOPKN;
    for (int kk = 0; kk < TOPKN; ++kk) {
        float v = taken ? -INFINITY : val;
        float m = v;
#pragma unroll
        for (int off = 32; off; off >>= 1) m = fmaxf(m, __shfl_xor(m, off, 64));
        unsigned long long msk = __ballot((!taken) && (val == m));
        int first = __ffsll(msk) - 1;
        if (lane == first) taken = true;
        if (lane == kk) dst[kk] = (m <= -BIGF * 0.5f) ? -1.0f : (float)first;
    }
}

// ---------------------------------------------------------------------------
extern "C" void kernel_launch(void* const* d_in, const int* in_sizes, int n_in,
                              void* d_out, int out_size, void* d_ws, size_t ws_size,
                              hipStream_t stream) {
    const float* q         = (const float*)d_in[0];
    const float* kv_lora   = (const float*)d_in[1];
    const float* k_pe      = (const float*)d_in[2];
    const float* W_cmp_kv  = (const float*)d_in[3];
    const float* W_cmp_kpe = (const float*)d_in[4];
    const float* W_kv_b    = (const float*)d_in[5];
    float* out = (float*)d_out;
    char* W = (char*)d_ws;

    // byte offsets (all 16-aligned)
    float* cmp_kv        = (float*)W;                         // 1,044,480 B
    float* cmp_pe        = (float*)(W + 1044480);             //   130,560 B
    unsigned int* p_agg  = (unsigned int*)(W + 1175040);      // 8,355,840 B
    unsigned short* kh_g = (unsigned short*)(W + 9530880);    // 3,133,440 B
    unsigned short* kl_g = (unsigned short*)(W + 12664320);   // 3,133,440 B
    unsigned short* vT_g = (unsigned short*)(W + 15797760);   // 2,097,152 B
    float* ph            = (float*)(W + 17894912);            // 134,217,728 B
    unsigned short* kvh  = (unsigned short*)(W + 152112640);  //   8,388,608 B
    unsigned short* kvl  = (unsigned short*)(W + 160501248);  //   8,388,608 B
    unsigned short* Wth  = (unsigned short*)(W + 168889856);  //  16,777,216 B
    unsigned short* Wtl  = (unsigned short*)(W + 185667072);  //  16,777,216 B
                                                              // end 202,444,288 B
    const bool plane = (ws_size >= (size_t)152112640);
    const bool mfma1 = (ws_size >= (size_t)202444288);
    float* ph_arg = plane ? ph : nullptr;

    hipMemsetAsync(cmp_kv, 0, (size_t)1044480, stream);
    if (!plane) hipMemsetAsync(p_agg, 0, (size_t)8355840, stream);
    hipMemsetAsync(vT_g, 0, (size_t)2097152, stream);   // n=255 column stays 0.0

    if (mfma1) {
        g0_kvsplit<<<dim3(2048),       256, 0, stream>>>(kv_lora, kvh, kvl);
        g0_wtsplit<<<dim3(256, 8),     256, 0, stream>>>(W_cmp_kv, Wth, Wtl);
        g1_mfma   <<<dim3(4, 8, 8),    512, 0, stream>>>(kvh, kvl, Wth, Wtl, cmp_kv);
    } else {
        g1_cmpkv  <<<dim3(4, 8, 16),   256, 0, stream>>>(kv_lora, W_cmp_kv, cmp_kv);
    }
    g1b_cmppe <<<dim3(510),      256, 0, stream>>>(k_pe, W_cmp_kpe, cmp_pe);
    g2_kvb    <<<dim3(8, 64),    256, 0, stream>>>(cmp_kv, W_kv_b, kh_g, kl_g, vT_g);
    g2b_pefill<<<dim3(2040),     256, 0, stream>>>(cmp_pe, kh_g, kl_g);
    g3_attn   <<<dim3(64, 32),   512, 0, stream>>>(q, kh_g, kl_g, vT_g, out, p_agg,
                                                   ph_arg);
    if (plane)
        g3b_pmax <<<dim3(8192),  256, 0, stream>>>(ph, (float*)p_agg);
    g4_topk   <<<dim3(2048),     256, 0, stream>>>((const float*)p_agg, out + 16777216);
}